// Round 3
// baseline (273.205 us; speedup 1.0000x reference)
//
#include <hip/hip_runtime.h>
#include <hip/hip_bf16.h>

#define NODES 50000
#define EDGES 800000
#define CH 128
#define NCOL 512           // packed cols per node: [ym1 | yv1 | ym2 | yv2]
#define MPAD 50048         // 391 * 128
#define EPW 8              // edges per wave in k_edges

typedef __attribute__((ext_vector_type(8))) __bf16 bf16x8;
typedef __attribute__((ext_vector_type(4))) float f32x4;
typedef unsigned long long u64;

static __device__ __forceinline__ unsigned short f2bf(float f) {
    union { float f; unsigned u; } v; v.f = f;
    unsigned r = v.u + 0x7FFFu + ((v.u >> 16) & 1u);   // RNE
    return (unsigned short)(r >> 16);
}
static __device__ __forceinline__ float bf2f(unsigned short h) {
    union { unsigned u; float f; } v; v.u = ((unsigned)h) << 16;
    return v.f;
}

// ---- phase 0a: x fp32 -> bf16, padded to MPAD rows (pad rows = 0) ----
__global__ void k_cvt_x(const float* __restrict__ x, unsigned short* __restrict__ xb) {
    int i = blockIdx.x * blockDim.x + threadIdx.x;      // one group of 4 elems
    if (i >= MPAD * CH / 4) return;
    int base = i << 2;
    unsigned short s0 = 0, s1 = 0, s2 = 0, s3 = 0;
    if (base < NODES * CH) {                            // groups never straddle
        const f32x4 v = *reinterpret_cast<const f32x4*>(x + base);
        s0 = f2bf(v[0]); s1 = f2bf(v[1]); s2 = f2bf(v[2]); s3 = f2bf(v[3]);
    }
    u64 p = (u64)s0 | ((u64)s1 << 16) | ((u64)s2 << 32) | ((u64)s3 << 48);
    *reinterpret_cast<u64*>(xb + base) = p;
}

// ---- phase 0b: pack weights into Wb[512][128] bf16 (B^T layout) ----
// col n: [0,128) ym1 = w_mean[n][k]           [128,256) yv1 = w_var[n-128][k]
//        [256,384) ym2 = w_mean[n-256][128+k] [384,512) yv2 = w_var[n-384][128+k]
__global__ void k_pack_w(const float* __restrict__ wm, const float* __restrict__ wv,
                         unsigned short* __restrict__ wb) {
    int i = blockIdx.x * blockDim.x + threadIdx.x;      // 0..65535
    if (i >= NCOL * CH) return;
    int n = i >> 7, k = i & 127;
    float v;
    if (n < 128)      v = wm[n * 256 + k];
    else if (n < 256) v = wv[(n - 128) * 256 + k];
    else if (n < 384) v = wm[(n - 256) * 256 + 128 + k];
    else              v = wv[(n - 384) * 256 + 128 + k];
    wb[i] = f2bf(v);
}

// ---- phase 1: tab[MPAD][512](bf16) = Xb[MPAD][128] @ Wb[512][128]^T (MFMA) ----
// LDS-free: K=128 total; B is 128 KB (L2-resident), A streamed.
__global__ __launch_bounds__(256) void k_gemm(const unsigned short* __restrict__ xb,
                                              const unsigned short* __restrict__ wb,
                                              unsigned short* __restrict__ th) {
    const int lane = threadIdx.x & 63;
    const int wave = threadIdx.x >> 6;
    const int rowbase = blockIdx.x * 128 + (wave >> 1) * 64;
    const int colbase = blockIdx.y * 128 + (wave & 1) * 64;
    const int lr = lane & 15;
    const int kg = lane >> 4;          // 0..3
    f32x4 acc[4][4] = {};
#pragma unroll
    for (int ks = 0; ks < 4; ++ks) {
        const int k = ks * 32 + kg * 8;
        bf16x8 af[4], bfr[4];
#pragma unroll
        for (int a = 0; a < 4; ++a)
            af[a] = *reinterpret_cast<const bf16x8*>(xb + (size_t)(rowbase + a * 16 + lr) * CH + k);
#pragma unroll
        for (int b = 0; b < 4; ++b)
            bfr[b] = *reinterpret_cast<const bf16x8*>(wb + (size_t)(colbase + b * 16 + lr) * CH + k);
#pragma unroll
        for (int a = 0; a < 4; ++a)
#pragma unroll
            for (int b = 0; b < 4; ++b)
                acc[a][b] = __builtin_amdgcn_mfma_f32_16x16x32_bf16(af[a], bfr[b], acc[a][b], 0, 0, 0);
    }
    // C/D layout: col = lane&15, row = (lane>>4)*4 + reg  [m89-verified]
    const int crow = (lane >> 4) * 4;
    const int ccol = lane & 15;
#pragma unroll
    for (int a = 0; a < 4; ++a)
#pragma unroll
        for (int b = 0; b < 4; ++b)
#pragma unroll
            for (int j = 0; j < 4; ++j) {
                int row = rowbase + a * 16 + crow + j;
                int col = colbase + b * 16 + ccol;
                th[(size_t)row * NCOL + col] = f2bf(acc[a][b][j]);
            }
}

// ---- phase 2: per-edge gather+add, EPW edges per wave for MLP ----
// lanes 0..31: mean (ym1[r] + ym2[c]); lanes 32..63: var (yv1[r] + yv2[c]).
// Row-r data = bytes [0,512) of node row r (whole-wave contiguous); row-c = [512,1024).
__global__ __launch_bounds__(256) void k_edges(const int* __restrict__ ei,
                                               const unsigned short* __restrict__ th,
                                               float* __restrict__ out) {
    const int wave = threadIdx.x >> 6;                  // wave-uniform
    const int lane = threadIdx.x & 63;
    const int half = lane >> 5;                         // 0 = mean, 1 = var
    const int l = lane & 31;
    const int ebase = (blockIdx.x * 4 + wave) * EPW;    // wave-uniform

    int rr[EPW], cc[EPW];
#pragma unroll
    for (int i = 0; i < EPW; ++i) {
        rr[i] = ei[ebase + i];
        cc[i] = ei[EDGES + ebase + i];
    }
    u64 pa[EPW], pb[EPW];
#pragma unroll
    for (int i = 0; i < EPW; ++i) {
        pa[i] = *reinterpret_cast<const u64*>(th + (size_t)rr[i] * NCOL + half * 128 + l * 4);
        pb[i] = *reinterpret_cast<const u64*>(th + (size_t)cc[i] * NCOL + 256 + half * 128 + l * 4);
    }
    const size_t obase = (size_t)half * ((size_t)EDGES * 128) + (size_t)l * 4;
#pragma unroll
    for (int i = 0; i < EPW; ++i) {
        f32x4 s;
        s[0] = bf2f((unsigned short)pa[i])         + bf2f((unsigned short)pb[i]);
        s[1] = bf2f((unsigned short)(pa[i] >> 16)) + bf2f((unsigned short)(pb[i] >> 16));
        s[2] = bf2f((unsigned short)(pa[i] >> 32)) + bf2f((unsigned short)(pb[i] >> 32));
        s[3] = bf2f((unsigned short)(pa[i] >> 48)) + bf2f((unsigned short)(pb[i] >> 48));
        __builtin_nontemporal_store(
            s, reinterpret_cast<f32x4*>(out + obase + (size_t)(ebase + i) * 128));
    }
}

// ---- last-resort fallback if ws is tiny: direct fp32 per-edge GEMV ----
__global__ void k_naive(const float* __restrict__ x, const int* __restrict__ ei,
                        const float* __restrict__ wm, const float* __restrict__ wv,
                        float* __restrict__ out) {
    __shared__ float xs[256];
    int e = blockIdx.x;
    int t = threadIdx.x;
    int r = ei[e], c = ei[EDGES + e];
    xs[t] = (t < 128) ? x[(size_t)r * 128 + t] : x[(size_t)c * 128 + (t - 128)];
    __syncthreads();
    const float* w = (t < 128) ? (wm + (size_t)t * 256) : (wv + (size_t)(t - 128) * 256);
    float acc = 0.f;
#pragma unroll 8
    for (int k = 0; k < 256; ++k) acc = fmaf(xs[k], w[k], acc);
    size_t ooff = (t < 128) ? ((size_t)e * 128 + t)
                            : ((size_t)EDGES * 128 + (size_t)e * 128 + (t - 128));
    out[ooff] = acc;
}

extern "C" void kernel_launch(void* const* d_in, const int* in_sizes, int n_in,
                              void* d_out, int out_size, void* d_ws, size_t ws_size,
                              hipStream_t stream) {
    const float* x  = (const float*)d_in[0];
    const int*   ei = (const int*)d_in[1];
    const float* wm = (const float*)d_in[2];
    const float* wv = (const float*)d_in[3];
    float* out = (float*)d_out;

    const size_t xb_b = (size_t)MPAD * CH * 2;     // 12,812,288 B
    const size_t wb_b = (size_t)NCOL * CH * 2;     //    131,072 B
    const size_t th_b = (size_t)MPAD * NCOL * 2;   //  51,249,152 B (bf16 tables)

    if (ws_size < xb_b + wb_b + th_b) {            // correctness insurance only
        k_naive<<<EDGES, 256, 0, stream>>>(x, ei, wm, wv, out);
        return;
    }

    unsigned short* xb  = (unsigned short*)d_ws;
    unsigned short* wb  = (unsigned short*)((char*)d_ws + xb_b);
    unsigned short* tab = (unsigned short*)((char*)d_ws + xb_b + wb_b);

    k_cvt_x<<<(MPAD * CH / 4 + 255) / 256, 256, 0, stream>>>(x, xb);
    k_pack_w<<<(NCOL * CH + 255) / 256, 256, 0, stream>>>(wm, wv, wb);
    dim3 g(MPAD / 128, NCOL / 128);
    k_gemm<<<g, 256, 0, stream>>>(xb, wb, tab);
    k_edges<<<EDGES / (4 * EPW), 256, 0, stream>>>(ei, tab, out);
}

// Round 4
// 267.292 us; speedup vs baseline: 1.0221x; 1.0221x over previous
//
#include <hip/hip_runtime.h>
#include <hip/hip_bf16.h>

#define NODES 50000
#define EDGES 800000
#define CH 128
#define NCOL 512           // packed cols per node: [ym1 | yv1 | ym2 | yv2]
#define MPAD 50048         // 391 * 128
#define EPW 8              // edges per wave in k_edges
#define NB 196             // r-buckets: bucket = r >> 8 (256 rows = 256 KB window)
#define BINBLK 256         // blocks in binning kernels
#define CHUNK 3125         // edges per binning block (256*3125 = 800000)

typedef __attribute__((ext_vector_type(8))) __bf16 bf16x8;
typedef __attribute__((ext_vector_type(4))) float f32x4;
typedef unsigned long long u64;

static __device__ __forceinline__ unsigned short f2bf(float f) {
    union { float f; unsigned u; } v; v.f = f;
    unsigned r = v.u + 0x7FFFu + ((v.u >> 16) & 1u);   // RNE
    return (unsigned short)(r >> 16);
}
static __device__ __forceinline__ float bf2f(unsigned short h) {
    union { unsigned u; float f; } v; v.u = ((unsigned)h) << 16;
    return v.f;
}

// ---- phase 0a: x fp32 -> bf16, padded to MPAD rows (pad rows = 0) ----
__global__ void k_cvt_x(const float* __restrict__ x, unsigned short* __restrict__ xb) {
    int i = blockIdx.x * blockDim.x + threadIdx.x;
    if (i >= MPAD * CH / 4) return;
    int base = i << 2;
    unsigned short s0 = 0, s1 = 0, s2 = 0, s3 = 0;
    if (base < NODES * CH) {
        const f32x4 v = *reinterpret_cast<const f32x4*>(x + base);
        s0 = f2bf(v[0]); s1 = f2bf(v[1]); s2 = f2bf(v[2]); s3 = f2bf(v[3]);
    }
    u64 p = (u64)s0 | ((u64)s1 << 16) | ((u64)s2 << 32) | ((u64)s3 << 48);
    *reinterpret_cast<u64*>(xb + base) = p;
}

// ---- phase 0b: pack weights into Wb[512][128] bf16 (B^T layout) ----
__global__ void k_pack_w(const float* __restrict__ wm, const float* __restrict__ wv,
                         unsigned short* __restrict__ wb) {
    int i = blockIdx.x * blockDim.x + threadIdx.x;
    if (i >= NCOL * CH) return;
    int n = i >> 7, k = i & 127;
    float v;
    if (n < 128)      v = wm[n * 256 + k];
    else if (n < 256) v = wv[(n - 128) * 256 + k];
    else if (n < 384) v = wm[(n - 256) * 256 + 128 + k];
    else              v = wv[(n - 384) * 256 + 128 + k];
    wb[i] = f2bf(v);
}

// ---- phase 1: tab[MPAD][512](bf16) = Xb @ Wb^T (MFMA 16x16x32) ----
__global__ __launch_bounds__(256) void k_gemm(const unsigned short* __restrict__ xb,
                                              const unsigned short* __restrict__ wb,
                                              unsigned short* __restrict__ th) {
    const int lane = threadIdx.x & 63;
    const int wave = threadIdx.x >> 6;
    const int rowbase = blockIdx.x * 128 + (wave >> 1) * 64;
    const int colbase = blockIdx.y * 128 + (wave & 1) * 64;
    const int lr = lane & 15;
    const int kg = lane >> 4;
    f32x4 acc[4][4] = {};
#pragma unroll
    for (int ks = 0; ks < 4; ++ks) {
        const int k = ks * 32 + kg * 8;
        bf16x8 af[4], bfr[4];
#pragma unroll
        for (int a = 0; a < 4; ++a)
            af[a] = *reinterpret_cast<const bf16x8*>(xb + (size_t)(rowbase + a * 16 + lr) * CH + k);
#pragma unroll
        for (int b = 0; b < 4; ++b)
            bfr[b] = *reinterpret_cast<const bf16x8*>(wb + (size_t)(colbase + b * 16 + lr) * CH + k);
#pragma unroll
        for (int a = 0; a < 4; ++a)
#pragma unroll
            for (int b = 0; b < 4; ++b)
                acc[a][b] = __builtin_amdgcn_mfma_f32_16x16x32_bf16(af[a], bfr[b], acc[a][b], 0, 0, 0);
    }
    const int crow = (lane >> 4) * 4;   // C/D: col = lane&15, row = (lane>>4)*4 + reg
    const int ccol = lane & 15;
#pragma unroll
    for (int a = 0; a < 4; ++a)
#pragma unroll
        for (int b = 0; b < 4; ++b)
#pragma unroll
            for (int j = 0; j < 4; ++j) {
                int row = rowbase + a * 16 + crow + j;
                int col = colbase + b * 16 + ccol;
                th[(size_t)row * NCOL + col] = f2bf(acc[a][b][j]);
            }
}

// ---- binning: counting sort of edges by r-bucket (r>>8), 196 buckets ----
__global__ void k_zero(unsigned* __restrict__ hist) {
    if (threadIdx.x < 256) hist[threadIdx.x] = 0;
}

__global__ __launch_bounds__(256) void k_binA(const int* __restrict__ ei,
                                              unsigned* __restrict__ hist,
                                              unsigned* __restrict__ blockOff) {
    __shared__ unsigned h[NB];
    for (int t = threadIdx.x; t < NB; t += 256) h[t] = 0;
    __syncthreads();
    const int base = blockIdx.x * CHUNK;
    for (int i = threadIdx.x; i < CHUNK; i += 256)
        atomicAdd(&h[((unsigned)ei[base + i]) >> 8], 1u);
    __syncthreads();
    for (int t = threadIdx.x; t < NB; t += 256)
        blockOff[blockIdx.x * NB + t] = atomicAdd(&hist[t], h[t]);
}

__global__ void k_scan(const unsigned* __restrict__ hist, unsigned* __restrict__ basearr) {
    __shared__ unsigned v[256];
    int t = threadIdx.x;
    unsigned mine = (t < NB) ? hist[t] : 0;
    v[t] = mine;
    __syncthreads();
    for (int off = 1; off < 256; off <<= 1) {
        unsigned x = (t >= off) ? v[t - off] : 0;
        __syncthreads();
        v[t] += x;
        __syncthreads();
    }
    if (t < NB) basearr[t] = v[t] - mine;   // exclusive prefix
}

__global__ __launch_bounds__(256) void k_binB(const int* __restrict__ ei,
                                              const unsigned* __restrict__ basearr,
                                              const unsigned* __restrict__ blockOff,
                                              u64* __restrict__ binned) {
    __shared__ unsigned cur[NB];
    for (int t = threadIdx.x; t < NB; t += 256) cur[t] = 0;
    __syncthreads();
    const int base = blockIdx.x * CHUNK;
    for (int i = threadIdx.x; i < CHUNK; i += 256) {
        int e = base + i;
        unsigned r = (unsigned)ei[e];
        unsigned c = (unsigned)ei[EDGES + e];
        unsigned b = r >> 8;
        unsigned rank = atomicAdd(&cur[b], 1u);
        unsigned pos = basearr[b] + blockOff[blockIdx.x * NB + b] + rank;
        binned[pos] = (u64)r | ((u64)c << 17) | ((u64)e << 34);
    }
}

// ---- phase 2: gather+add over r-binned edges (r-window L2-resident) ----
__global__ __launch_bounds__(256) void k_edges_b(const u64* __restrict__ binned,
                                                 const unsigned short* __restrict__ th,
                                                 float* __restrict__ out) {
    const int wave = threadIdx.x >> 6;
    const int lane = threadIdx.x & 63;
    const int half = lane >> 5;                  // 0 = mean, 1 = var
    const int l = lane & 31;
    const int ebase = (blockIdx.x * 4 + wave) * EPW;

    u64 rec[EPW];
#pragma unroll
    for (int i = 0; i < EPW; ++i) rec[i] = binned[ebase + i];   // broadcast loads
    u64 pa[EPW], pb[EPW];
#pragma unroll
    for (int i = 0; i < EPW; ++i) {
        const unsigned r = (unsigned)(rec[i] & 0x1FFFF);
        const unsigned c = (unsigned)((rec[i] >> 17) & 0x1FFFF);
        pa[i] = *reinterpret_cast<const u64*>(th + (size_t)r * NCOL + half * 128 + l * 4);
        pb[i] = *reinterpret_cast<const u64*>(th + (size_t)c * NCOL + 256 + half * 128 + l * 4);
    }
    const size_t obase = (size_t)half * ((size_t)EDGES * 128) + (size_t)l * 4;
#pragma unroll
    for (int i = 0; i < EPW; ++i) {
        const unsigned e = (unsigned)(rec[i] >> 34);
        f32x4 s;
        s[0] = bf2f((unsigned short)pa[i])         + bf2f((unsigned short)pb[i]);
        s[1] = bf2f((unsigned short)(pa[i] >> 16)) + bf2f((unsigned short)(pb[i] >> 16));
        s[2] = bf2f((unsigned short)(pa[i] >> 32)) + bf2f((unsigned short)(pb[i] >> 32));
        s[3] = bf2f((unsigned short)(pa[i] >> 48)) + bf2f((unsigned short)(pb[i] >> 48));
        __builtin_nontemporal_store(
            s, reinterpret_cast<f32x4*>(out + obase + (size_t)e * 128));
    }
}

// ---- unbinned fallback (ws too small for binned array) ----
__global__ __launch_bounds__(256) void k_edges(const int* __restrict__ ei,
                                               const unsigned short* __restrict__ th,
                                               float* __restrict__ out) {
    const int wave = threadIdx.x >> 6;
    const int lane = threadIdx.x & 63;
    const int half = lane >> 5;
    const int l = lane & 31;
    const int ebase = (blockIdx.x * 4 + wave) * EPW;
    int rr[EPW], cc[EPW];
#pragma unroll
    for (int i = 0; i < EPW; ++i) { rr[i] = ei[ebase + i]; cc[i] = ei[EDGES + ebase + i]; }
    u64 pa[EPW], pb[EPW];
#pragma unroll
    for (int i = 0; i < EPW; ++i) {
        pa[i] = *reinterpret_cast<const u64*>(th + (size_t)rr[i] * NCOL + half * 128 + l * 4);
        pb[i] = *reinterpret_cast<const u64*>(th + (size_t)cc[i] * NCOL + 256 + half * 128 + l * 4);
    }
    const size_t obase = (size_t)half * ((size_t)EDGES * 128) + (size_t)l * 4;
#pragma unroll
    for (int i = 0; i < EPW; ++i) {
        f32x4 s;
        s[0] = bf2f((unsigned short)pa[i])         + bf2f((unsigned short)pb[i]);
        s[1] = bf2f((unsigned short)(pa[i] >> 16)) + bf2f((unsigned short)(pb[i] >> 16));
        s[2] = bf2f((unsigned short)(pa[i] >> 32)) + bf2f((unsigned short)(pb[i] >> 32));
        s[3] = bf2f((unsigned short)(pa[i] >> 48)) + bf2f((unsigned short)(pb[i] >> 48));
        __builtin_nontemporal_store(
            s, reinterpret_cast<f32x4*>(out + obase + (size_t)(ebase + i) * 128));
    }
}

// ---- last-resort fallback: direct fp32 per-edge GEMV ----
__global__ void k_naive(const float* __restrict__ x, const int* __restrict__ ei,
                        const float* __restrict__ wm, const float* __restrict__ wv,
                        float* __restrict__ out) {
    __shared__ float xs[256];
    int e = blockIdx.x;
    int t = threadIdx.x;
    int r = ei[e], c = ei[EDGES + e];
    xs[t] = (t < 128) ? x[(size_t)r * 128 + t] : x[(size_t)c * 128 + (t - 128)];
    __syncthreads();
    const float* w = (t < 128) ? (wm + (size_t)t * 256) : (wv + (size_t)(t - 128) * 256);
    float acc = 0.f;
#pragma unroll 8
    for (int k = 0; k < 256; ++k) acc = fmaf(xs[k], w[k], acc);
    size_t ooff = (t < 128) ? ((size_t)e * 128 + t)
                            : ((size_t)EDGES * 128 + (size_t)e * 128 + (t - 128));
    out[ooff] = acc;
}

extern "C" void kernel_launch(void* const* d_in, const int* in_sizes, int n_in,
                              void* d_out, int out_size, void* d_ws, size_t ws_size,
                              hipStream_t stream) {
    const float* x  = (const float*)d_in[0];
    const int*   ei = (const int*)d_in[1];
    const float* wm = (const float*)d_in[2];
    const float* wv = (const float*)d_in[3];
    float* out = (float*)d_out;

    const size_t xb_b   = (size_t)MPAD * CH * 2;        // 12,812,288
    const size_t wb_b   = (size_t)NCOL * CH * 2;        //    131,072
    const size_t th_b   = (size_t)MPAD * NCOL * 2;      // 51,249,152
    const size_t hist_b = 1024;                         // 256 u32
    const size_t base_b = 1024;
    const size_t boff_b = (size_t)BINBLK * NB * 4;      // 200,704
    const size_t bin_b  = (size_t)EDGES * 8;            // 6,400,000

    const size_t need_tab = xb_b + wb_b + th_b;
    const size_t need_bin = need_tab + hist_b + base_b + boff_b + bin_b;

    if (ws_size < need_tab) {                 // correctness insurance only
        k_naive<<<EDGES, 256, 0, stream>>>(x, ei, wm, wv, out);
        return;
    }

    char* w0 = (char*)d_ws;
    unsigned short* xb  = (unsigned short*)w0;
    unsigned short* wb  = (unsigned short*)(w0 + xb_b);
    unsigned short* tab = (unsigned short*)(w0 + xb_b + wb_b);

    k_cvt_x<<<(MPAD * CH / 4 + 255) / 256, 256, 0, stream>>>(x, xb);
    k_pack_w<<<(NCOL * CH + 255) / 256, 256, 0, stream>>>(wm, wv, wb);
    dim3 g(MPAD / 128, NCOL / 128);
    k_gemm<<<g, 256, 0, stream>>>(xb, wb, tab);

    if (ws_size >= need_bin) {
        unsigned* hist    = (unsigned*)(w0 + need_tab);
        unsigned* basearr = (unsigned*)(w0 + need_tab + hist_b);
        unsigned* boff    = (unsigned*)(w0 + need_tab + hist_b + base_b);
        u64*      binned  = (u64*)    (w0 + need_tab + hist_b + base_b + boff_b);
        k_zero<<<1, 256, 0, stream>>>(hist);
        k_binA<<<BINBLK, 256, 0, stream>>>(ei, hist, boff);
        k_scan<<<1, 256, 0, stream>>>(hist, basearr);
        k_binB<<<BINBLK, 256, 0, stream>>>(ei, basearr, boff, binned);
        k_edges_b<<<EDGES / (4 * EPW), 256, 0, stream>>>(binned, tab, out);
    } else {
        k_edges<<<EDGES / (4 * EPW), 256, 0, stream>>>(ei, tab, out);
    }
}